// Round 3
// baseline (633.595 us; speedup 1.0000x reference)
//
#include <hip/hip_runtime.h>
#include <hip/hip_bf16.h>

// InteractingLayer: B=16384, F=40, E=64, H=4, D=32, OUT=128
// One block (256 thr, 4 waves) per batch element. Wave w owns head w
// END-TO-END: computes Q/K/V/R column-slices [32w,32w+32) itself, then does
// head-w attention. Q/K NEVER touch LDS (C-layout -> A/B-operand via quad
// shuffles). LDS = x-staging + per-head Vt: 24960 B -> 6 blocks/CU.
// R4: epilogue restored to full-line float4 stores. relu(O+R) is staged fp32
// in LDS (entire block is dead after a second barrier: xb consumed into xf
// regs, all Vt consumed by PV) at stride 36 floats -> 2-way-free writes,
// conflict-free reads, then 1KB-contiguous per-wave global stores.
// (R2's register-direct dword stores caused 2x HBM write amplification:
// 64B partial-line RMW; WRITE_SIZE 327MB->639MB, dur 270->299.)

#define F_DIM 40
#define O_DIM 128

typedef __bf16 bf16x8 __attribute__((ext_vector_type(8)));
typedef __bf16 bf16x2 __attribute__((ext_vector_type(2)));
typedef float  f32x4  __attribute__((ext_vector_type(4)));

// ---- LDS map (ushort units) ----
// xb [48][68] @ 0 (3264)  shared x staging (bf16), rows 40..47 zeroed
//   stride 68 ushort = 136 B = 34 banks (≡2 mod 32): conflict-free ld8/st8
// per head h @ 3264 + h*2304 (wave-private):
//   Vt [32][72]  cols 48..63 zeroed; 64..71 pad (never read by PV)
// After barrier #2: whole block reused as 4x wave-private fp32 out-stage
//   os_w = [40][36] f32 @ byte offset w*5760 (23040 B total)
#define XBS 68
#define VTS 72
#define OSS 36
#define HB0 3264
#define HSZ 2304
#define TOT 12480   // ushorts = 24960 B -> 6 blocks/CU

static __device__ __forceinline__ unsigned pk2(float a, float b) {
  // native f32->bf16 (RNE) pair -> compiler emits one v_cvt_pk_bf16_f32
  bf16x2 t;
  t[0] = (__bf16)a;
  t[1] = (__bf16)b;
  return __builtin_bit_cast(unsigned, t);
}
static __device__ __forceinline__ float bf2f(unsigned short h) {
  unsigned u = ((unsigned)h) << 16;
  return __builtin_bit_cast(float, u);
}
union V8 { uint2 u2[2]; uint4 u4; unsigned u[4]; bf16x8 v; };
static __device__ __forceinline__ bf16x8 lds_ld8(const unsigned short* p) {   // 8B-aligned
  V8 t; t.u2[0] = *(const uint2*)p; t.u2[1] = *(const uint2*)(p + 4); return t.v;
}
static __device__ __forceinline__ bf16x8 lds_ld16(const unsigned short* p) {  // 16B-aligned
  V8 t; t.u4 = *(const uint4*)p; return t.v;
}
static __device__ __forceinline__ f32x4 mfma16(bf16x8 a, bf16x8 b, f32x4 c) {
  return __builtin_amdgcn_mfma_f32_16x16x32_bf16(a, b, c, 0, 0, 0);
}

#if __has_builtin(__builtin_amdgcn_exp2f)
#define EXP2F __builtin_amdgcn_exp2f
#else
#define EXP2F exp2f
#endif
#if __has_builtin(__builtin_amdgcn_rcpf)
#define RCPF __builtin_amdgcn_rcpf
#else
#define RCPF(x) (1.0f / (x))
#endif

__global__ void convert_weights(const float* __restrict__ Wq, const float* __restrict__ Wk,
                                const float* __restrict__ Wv, const float* __restrict__ Wr,
                                unsigned short* __restrict__ ws) {
  int i = blockIdx.x * 256 + threadIdx.x;   // 0..32767
  const float* src = (i < 8192) ? Wq : (i < 16384) ? Wk : (i < 24576) ? Wv : Wr;
  ws[i] = __builtin_bit_cast(unsigned short, (__bf16)src[i & 8191]);
}

__global__ __launch_bounds__(256, 6) void interact_kernel(
    const float* __restrict__ x, const unsigned short* __restrict__ wbf,
    const float* __restrict__ bq, const float* __restrict__ bk,
    const float* __restrict__ bv, const float* __restrict__ br,
    float* __restrict__ out) {
  __shared__ __align__(16) unsigned short sm[TOT];
  const int t = threadIdx.x;
  const int w = t >> 6;        // wave = head
  const int l = t & 63;
  const int c = l & 15;        // MFMA lane-column
  const int q = l >> 4;        // quad
  const int b = blockIdx.x;
  f32x4 z4 = {0.f, 0.f, 0.f, 0.f};

  // quad-shuffle source lanes for all C-layout -> A/B-operand transforms:
  // target (c,q) elem pair a pulls from lane 16*(2(q&1)+(a>>1)) + c
  const int srcA0 = 16 * (2 * (q & 1) + 0) + c;   // a = 0,1
  const int srcA1 = 16 * (2 * (q & 1) + 1) + c;   // a = 2,3

  // ---------- Phase A: stage x -> LDS bf16 (shared); zero pad rows ----------
  const float* xp = x + (size_t)b * (F_DIM * 64);
  for (int i = t; i < 640; i += 256) {                       // 640 float4 = 40x64
    float4 v4 = reinterpret_cast<const float4*>(xp)[i];
    int f = i >> 4, e4 = (i & 15) << 2;
    uint2 pk; pk.x = pk2(v4.x, v4.y); pk.y = pk2(v4.z, v4.w);
    *reinterpret_cast<uint2*>(sm + f * XBS + e4) = pk;
  }
  {
    uint2 z; z.x = 0; z.y = 0;
    for (int i = t; i < 136; i += 256)                       // rows 40..47 = 0 (8*68/4)
      reinterpret_cast<uint2*>(sm + 40 * XBS)[i] = z;
  }
  __syncthreads();                                           // barrier #1

  unsigned short* Vtb = sm + HB0 + w * HSZ;

  // x fragments: rows f=c+16t, k=e in quads. Serves as A- and B-operand.
  bf16x8 xf[3][2];
#pragma unroll
  for (int nt = 0; nt < 3; ++nt)
#pragma unroll
    for (int ks = 0; ks < 2; ++ks)
      xf[nt][ks] = lds_ld8(sm + (c + 16 * nt) * XBS + 32 * ks + 8 * q);

  // ---------- Phase B ----------
  // V: D[f][d] (A=x rows f, B=W rows d); store transposed Vt[d][f] in LDS
#pragma unroll
  for (int nt = 0; nt < 2; ++nt) {
    const unsigned short* wr0 = wbf + 2 * 8192 + (32 * w + 16 * nt + c) * 64 + 8 * q;
    bf16x8 b0 = *reinterpret_cast<const bf16x8*>(wr0);
    bf16x8 b1 = *reinterpret_cast<const bf16x8*>(wr0 + 32);
    float bb = bv[32 * w + c + 16 * nt];
#pragma unroll
    for (int mt = 0; mt < 3; ++mt) {
      f32x4 acc = mfma16(xf[mt][1], b1, mfma16(xf[mt][0], b0, z4));
      uint2 pk;
      pk.x = pk2(acc[0] + bb, acc[1] + bb);
      pk.y = pk2(acc[2] + bb, acc[3] + bb);
      *reinterpret_cast<uint2*>(Vtb + (c + 16 * nt) * VTS + 16 * mt + 4 * q) = pk;
    }
  }
  {
    uint2 zz; zz.x = 0; zz.y = 0;                            // Vt[:,48..63] = 0
#pragma unroll
    for (int k2 = 0; k2 < 2; ++k2) {
      int idx = l + 64 * k2, row = idx >> 2, g4 = idx & 3;
      *reinterpret_cast<uint2*>(Vtb + row * VTS + 48 + 4 * g4) = zz;
    }
  }
  // R: D[f][d] — same layout as O; keep packed bf16 in registers (12 VGPR)
  unsigned rp[3][2][2];
#pragma unroll
  for (int nt = 0; nt < 2; ++nt) {
    const unsigned short* wr0 = wbf + 3 * 8192 + (32 * w + 16 * nt + c) * 64 + 8 * q;
    bf16x8 b0 = *reinterpret_cast<const bf16x8*>(wr0);
    bf16x8 b1 = *reinterpret_cast<const bf16x8*>(wr0 + 32);
#pragma unroll
    for (int mt = 0; mt < 3; ++mt) {
      f32x4 acc = mfma16(xf[mt][1], b1, mfma16(xf[mt][0], b0, z4));
      rp[mt][nt][0] = pk2(acc[0], acc[1]);
      rp[mt][nt][1] = pk2(acc[2], acc[3]);
    }
  }
  // Q,K: D[d][f] (A=W rows d, B=x rows f). Never stored: pack + quad-shuffle
  // straight into A/B-operand fragments (rows f=c+16gt, k=d=8q+j).
  //   target pair a: d=8q+2a -> src mt = q>>1, src quad 2(q&1)+(a>>1), pair a&1
  // Rows f in [40,48) come from zeroed x rows -> bias-only, finite; masked in
  // softmax (g-mask) / never stored (f-mask).
  bf16x8 qf[3], kf[3];
#pragma unroll
  for (int pr = 0; pr < 2; ++pr) {
    const unsigned short* Wm = wbf + pr * 8192 + 32 * w * 64;
    const float* Bp = pr ? bk : bq;
    unsigned qk[3][2][2];                                    // [nt=f-tile][mt][pair]
#pragma unroll
    for (int mt = 0; mt < 2; ++mt) {
      const unsigned short* wr0 = Wm + (16 * mt + c) * 64 + 8 * q;
      bf16x8 a0 = *reinterpret_cast<const bf16x8*>(wr0);
      bf16x8 a1 = *reinterpret_cast<const bf16x8*>(wr0 + 32);
      float4 bb = *reinterpret_cast<const float4*>(Bp + 32 * w + 16 * mt + 4 * q);
#pragma unroll
      for (int nt = 0; nt < 3; ++nt) {
        f32x4 acc = mfma16(a1, xf[nt][1], mfma16(a0, xf[nt][0], z4));
        qk[nt][mt][0] = pk2(acc[0] + bb.x, acc[1] + bb.y);
        qk[nt][mt][1] = pk2(acc[2] + bb.z, acc[3] + bb.w);
      }
    }
#pragma unroll
    for (int gt = 0; gt < 3; ++gt) {
      V8 f;
#pragma unroll
      for (int a = 0; a < 4; ++a) {
        int src = (a < 2) ? srcA0 : srcA1;
        unsigned v0 = (unsigned)__shfl((int)qk[gt][0][a & 1], src, 64);
        unsigned v1 = (unsigned)__shfl((int)qk[gt][1][a & 1], src, 64);
        f.u[a] = (q < 2) ? v0 : v1;                          // mt = q>>1
      }
      if (pr) kf[gt] = f.v; else qf[gt] = f.v;
    }
  }

  // ---------- Phase C: S^T = K Q^T (all-register), softmax over g ----------
  f32x4 s[3][3];
#pragma unroll
  for (int gt = 0; gt < 3; ++gt)
#pragma unroll
    for (int ft = 0; ft < 3; ++ft)
      s[gt][ft] = mfma16(kf[gt], qf[ft], z4);                // row g=16gt+4q+r, col f

  // softmax fused with P C-layout -> A-operand quad-shuffle (pp transient)
  bf16x8 pf[3][2];
  const float cexp = 0.125f * 1.44269504f;                   // 1/sqrt(64) * log2(e)
#pragma unroll
  for (int ft = 0; ft < 3; ++ft) {
    float m = -1e30f;
#pragma unroll
    for (int gt = 0; gt < 2; ++gt)
#pragma unroll
      for (int r = 0; r < 4; ++r) m = fmaxf(m, s[gt][ft][r]);
    if (q < 2) {
#pragma unroll
      for (int r = 0; r < 4; ++r) m = fmaxf(m, s[2][ft][r]);
    }
    m = fmaxf(m, __shfl_xor(m, 16, 64));
    m = fmaxf(m, __shfl_xor(m, 32, 64));
    float p[3][4]; float sum = 0.f;
#pragma unroll
    for (int gt = 0; gt < 3; ++gt)
#pragma unroll
      for (int r = 0; r < 4; ++r) {
        float pe = EXP2F((s[gt][ft][r] - m) * cexp);
        if (gt == 2 && q >= 2) pe = 0.f;                     // mask g=40..47
        p[gt][r] = pe; sum += pe;
      }
    sum += __shfl_xor(sum, 16, 64);
    sum += __shfl_xor(sum, 32, 64);
    float inv = RCPF(sum);
    unsigned pp[3][2];
#pragma unroll
    for (int gt = 0; gt < 3; ++gt) {
      pp[gt][0] = pk2(p[gt][0] * inv, p[gt][1] * inv);
      pp[gt][1] = pk2(p[gt][2] * inv, p[gt][3] * inv);
    }
    V8 f0, f1;
#pragma unroll
    for (int a = 0; a < 4; ++a) {
      int src = (a < 2) ? srcA0 : srcA1;
      unsigned v0 = (unsigned)__shfl((int)pp[0][a & 1], src, 64);
      unsigned v1 = (unsigned)__shfl((int)pp[1][a & 1], src, 64);
      unsigned v2 = (unsigned)__shfl((int)pp[2][a & 1], src, 64);
      f0.u[a] = (q < 2) ? v0 : v1;                           // ks=0: gt'=q>>1
      f1.u[a] = (q < 2) ? v2 : 0u;                           // ks=1: gt'=2 or zero
    }
    pf[ft][0] = f0.v; pf[ft][1] = f1.v;
  }

  // ---------- Phase D: O = P V ----------
  f32x4 o[3][2];
  {
    bf16x8 vb[2][2];
#pragma unroll
    for (int nt = 0; nt < 2; ++nt)
#pragma unroll
      for (int ks = 0; ks < 2; ++ks)
        vb[nt][ks] = lds_ld16(Vtb + (c + 16 * nt) * VTS + 32 * ks + 8 * q);
#pragma unroll
    for (int mt = 0; mt < 3; ++mt)
#pragma unroll
      for (int nt = 0; nt < 2; ++nt)
        o[mt][nt] = mfma16(pf[mt][1], vb[nt][1], mfma16(pf[mt][0], vb[nt][0], z4));
  }

  // ---------- Phase E: relu(O + R) -> LDS fp32 stage -> float4 full lines ----
  __syncthreads();   // barrier #2: xb + all Vt now dead; whole LDS reusable
  float* os = reinterpret_cast<float*>(sm) + w * (F_DIM * OSS);  // [40][36] f32
  float brv0 = br[32 * w + c], brv1 = br[32 * w + c + 16];
#pragma unroll
  for (int mt = 0; mt < 3; ++mt) {
    if (mt < 2 || q < 2) {
#pragma unroll
      for (int nt = 0; nt < 2; ++nt) {
        float bb = nt ? brv1 : brv0;
#pragma unroll
        for (int r = 0; r < 4; ++r) {
          int f = 16 * mt + 4 * q + r;
          unsigned pr_ = rp[mt][nt][r >> 1];
          float rv = bf2f((unsigned short)((r & 1) ? (pr_ >> 16) : (pr_ & 0xFFFFu)));
          os[f * OSS + c + 16 * nt] = fmaxf(o[mt][nt][r] + rv + bb, 0.f);
        }
      }
    }
  }
  // wave-private read-back (ds dependency handled by waitcnt, no barrier)
  float* op = out + (size_t)b * (F_DIM * O_DIM) + 32 * w;
#pragma unroll
  for (int it = 0; it < 5; ++it) {
    int i = 64 * it + l;
    int f = i >> 3, d4 = i & 7;
    float4 v = *reinterpret_cast<const float4*>(os + f * OSS + 4 * d4);
    *reinterpret_cast<float4*>(op + (size_t)f * O_DIM + 4 * d4) = v;
  }
}

extern "C" void kernel_launch(void* const* d_in, const int* in_sizes, int n_in,
                              void* d_out, int out_size, void* d_ws, size_t ws_size,
                              hipStream_t stream) {
  const float* x  = (const float*)d_in[0];
  const float* Wq = (const float*)d_in[1];
  const float* bq = (const float*)d_in[2];
  const float* Wk = (const float*)d_in[3];
  const float* bk = (const float*)d_in[4];
  const float* Wv = (const float*)d_in[5];
  const float* bv = (const float*)d_in[6];
  const float* Wr = (const float*)d_in[7];
  const float* br = (const float*)d_in[8];
  unsigned short* wbf = (unsigned short*)d_ws;               // 32768 bf16 = 64 KB
  float* out = (float*)d_out;
  convert_weights<<<128, 256, 0, stream>>>(Wq, Wk, Wv, Wr, wbf);
  interact_kernel<<<16384, 256, 0, stream>>>(x, wbf, bq, bk, bv, br, out);
}

// Round 4
// 606.587 us; speedup vs baseline: 1.0445x; 1.0445x over previous
//
#include <hip/hip_runtime.h>
#include <hip/hip_bf16.h>

// InteractingLayer: B=16384, F=40, E=64, H=4, D=32, OUT=128
// One block (256 thr, 4 waves) per batch element. Wave w owns head w
// END-TO-END: computes Q/K/V/R column-slices [32w,32w+32) itself, then does
// head-w attention. Q/K NEVER touch LDS (C-layout -> A/B-operand via quad
// shuffles). LDS = x-staging + per-head Vt: 24960 B -> 6 blocks/CU.
// R5: sector-atomic epilogue. At 6 blocks/CU the per-XCD stream footprint
// (~5.8MB) exceeds the 4MB L2, so 256B sectors written piecewise by
// different waves (each wave owns a 128B quarter-row) were evicted between
// partial writes -> RMW fetch + double writeback (R2/R3: WRITE 639/704MB vs
// 335MB output, FETCH +150MB). Fix: block-shared [40][132] fp32 stage after
// barrier #2, then cooperative linear copy: 1KB contiguous per wave-instr,
// every 256B sector written atomically. Same instr count as before.

#define F_DIM 40
#define O_DIM 128

typedef __bf16 bf16x8 __attribute__((ext_vector_type(8)));
typedef __bf16 bf16x2 __attribute__((ext_vector_type(2)));
typedef float  f32x4  __attribute__((ext_vector_type(4)));

// ---- LDS map (ushort units) ----
// xb [48][68] @ 0 (3264)  shared x staging (bf16), rows 40..47 zeroed
//   stride 68 ushort = 136 B = 34 banks (≡2 mod 32): conflict-free ld8/st8
// per head h @ 3264 + h*2304 (wave-private):
//   Vt [32][72]  cols 48..63 zeroed; 64..71 pad (never read by PV)
// After barrier #2: whole block reused as ONE block-shared fp32 out-stage
//   os = [40][132] f32 (21120 B; stride 132 -> staged writes 2-way-free,
//   cooperative float4 read-back is the conflict-free consecutive pattern)
#define XBS 68
#define VTS 72
#define OSS 132
#define HB0 3264
#define HSZ 2304
#define TOT 12480   // ushorts = 24960 B -> 6 blocks/CU

static __device__ __forceinline__ unsigned pk2(float a, float b) {
  // native f32->bf16 (RNE) pair -> compiler emits one v_cvt_pk_bf16_f32
  bf16x2 t;
  t[0] = (__bf16)a;
  t[1] = (__bf16)b;
  return __builtin_bit_cast(unsigned, t);
}
static __device__ __forceinline__ float bf2f(unsigned short h) {
  unsigned u = ((unsigned)h) << 16;
  return __builtin_bit_cast(float, u);
}
union V8 { uint2 u2[2]; uint4 u4; unsigned u[4]; bf16x8 v; };
static __device__ __forceinline__ bf16x8 lds_ld8(const unsigned short* p) {   // 8B-aligned
  V8 t; t.u2[0] = *(const uint2*)p; t.u2[1] = *(const uint2*)(p + 4); return t.v;
}
static __device__ __forceinline__ bf16x8 lds_ld16(const unsigned short* p) {  // 16B-aligned
  V8 t; t.u4 = *(const uint4*)p; return t.v;
}
static __device__ __forceinline__ f32x4 mfma16(bf16x8 a, bf16x8 b, f32x4 c) {
  return __builtin_amdgcn_mfma_f32_16x16x32_bf16(a, b, c, 0, 0, 0);
}

#if __has_builtin(__builtin_amdgcn_exp2f)
#define EXP2F __builtin_amdgcn_exp2f
#else
#define EXP2F exp2f
#endif
#if __has_builtin(__builtin_amdgcn_rcpf)
#define RCPF __builtin_amdgcn_rcpf
#else
#define RCPF(x) (1.0f / (x))
#endif

__global__ void convert_weights(const float* __restrict__ Wq, const float* __restrict__ Wk,
                                const float* __restrict__ Wv, const float* __restrict__ Wr,
                                unsigned short* __restrict__ ws) {
  int i = blockIdx.x * 256 + threadIdx.x;   // 0..32767
  const float* src = (i < 8192) ? Wq : (i < 16384) ? Wk : (i < 24576) ? Wv : Wr;
  ws[i] = __builtin_bit_cast(unsigned short, (__bf16)src[i & 8191]);
}

__global__ __launch_bounds__(256, 6) void interact_kernel(
    const float* __restrict__ x, const unsigned short* __restrict__ wbf,
    const float* __restrict__ bq, const float* __restrict__ bk,
    const float* __restrict__ bv, const float* __restrict__ br,
    float* __restrict__ out) {
  __shared__ __align__(16) unsigned short sm[TOT];
  const int t = threadIdx.x;
  const int w = t >> 6;        // wave = head
  const int l = t & 63;
  const int c = l & 15;        // MFMA lane-column
  const int q = l >> 4;        // quad
  const int b = blockIdx.x;
  f32x4 z4 = {0.f, 0.f, 0.f, 0.f};

  // quad-shuffle source lanes for all C-layout -> A/B-operand transforms:
  // target (c,q) elem pair a pulls from lane 16*(2(q&1)+(a>>1)) + c
  const int srcA0 = 16 * (2 * (q & 1) + 0) + c;   // a = 0,1
  const int srcA1 = 16 * (2 * (q & 1) + 1) + c;   // a = 2,3

  // ---------- Phase A: stage x -> LDS bf16 (shared); zero pad rows ----------
  const float* xp = x + (size_t)b * (F_DIM * 64);
  for (int i = t; i < 640; i += 256) {                       // 640 float4 = 40x64
    float4 v4 = reinterpret_cast<const float4*>(xp)[i];
    int f = i >> 4, e4 = (i & 15) << 2;
    uint2 pk; pk.x = pk2(v4.x, v4.y); pk.y = pk2(v4.z, v4.w);
    *reinterpret_cast<uint2*>(sm + f * XBS + e4) = pk;
  }
  {
    uint2 z; z.x = 0; z.y = 0;
    for (int i = t; i < 136; i += 256)                       // rows 40..47 = 0 (8*68/4)
      reinterpret_cast<uint2*>(sm + 40 * XBS)[i] = z;
  }
  __syncthreads();                                           // barrier #1

  unsigned short* Vtb = sm + HB0 + w * HSZ;

  // x fragments: rows f=c+16t, k=e in quads. Serves as A- and B-operand.
  bf16x8 xf[3][2];
#pragma unroll
  for (int nt = 0; nt < 3; ++nt)
#pragma unroll
    for (int ks = 0; ks < 2; ++ks)
      xf[nt][ks] = lds_ld8(sm + (c + 16 * nt) * XBS + 32 * ks + 8 * q);

  // ---------- Phase B ----------
  // V: D[f][d] (A=x rows f, B=W rows d); store transposed Vt[d][f] in LDS
#pragma unroll
  for (int nt = 0; nt < 2; ++nt) {
    const unsigned short* wr0 = wbf + 2 * 8192 + (32 * w + 16 * nt + c) * 64 + 8 * q;
    bf16x8 b0 = *reinterpret_cast<const bf16x8*>(wr0);
    bf16x8 b1 = *reinterpret_cast<const bf16x8*>(wr0 + 32);
    float bb = bv[32 * w + c + 16 * nt];
#pragma unroll
    for (int mt = 0; mt < 3; ++mt) {
      f32x4 acc = mfma16(xf[mt][1], b1, mfma16(xf[mt][0], b0, z4));
      uint2 pk;
      pk.x = pk2(acc[0] + bb, acc[1] + bb);
      pk.y = pk2(acc[2] + bb, acc[3] + bb);
      *reinterpret_cast<uint2*>(Vtb + (c + 16 * nt) * VTS + 16 * mt + 4 * q) = pk;
    }
  }
  {
    uint2 zz; zz.x = 0; zz.y = 0;                            // Vt[:,48..63] = 0
#pragma unroll
    for (int k2 = 0; k2 < 2; ++k2) {
      int idx = l + 64 * k2, row = idx >> 2, g4 = idx & 3;
      *reinterpret_cast<uint2*>(Vtb + row * VTS + 48 + 4 * g4) = zz;
    }
  }
  // R: D[f][d] — same layout as O; keep packed bf16 in registers (12 VGPR)
  unsigned rp[3][2][2];
#pragma unroll
  for (int nt = 0; nt < 2; ++nt) {
    const unsigned short* wr0 = wbf + 3 * 8192 + (32 * w + 16 * nt + c) * 64 + 8 * q;
    bf16x8 b0 = *reinterpret_cast<const bf16x8*>(wr0);
    bf16x8 b1 = *reinterpret_cast<const bf16x8*>(wr0 + 32);
#pragma unroll
    for (int mt = 0; mt < 3; ++mt) {
      f32x4 acc = mfma16(xf[mt][1], b1, mfma16(xf[mt][0], b0, z4));
      rp[mt][nt][0] = pk2(acc[0], acc[1]);
      rp[mt][nt][1] = pk2(acc[2], acc[3]);
    }
  }
  // Q,K: D[d][f] (A=W rows d, B=x rows f). Never stored: pack + quad-shuffle
  // straight into A/B-operand fragments (rows f=c+16gt, k=d=8q+j).
  //   target pair a: d=8q+2a -> src mt = q>>1, src quad 2(q&1)+(a>>1), pair a&1
  // Rows f in [40,48) come from zeroed x rows -> bias-only, finite; masked in
  // softmax (g-mask) / never stored (f-mask).
  bf16x8 qf[3], kf[3];
#pragma unroll
  for (int pr = 0; pr < 2; ++pr) {
    const unsigned short* Wm = wbf + pr * 8192 + 32 * w * 64;
    const float* Bp = pr ? bk : bq;
    unsigned qk[3][2][2];                                    // [nt=f-tile][mt][pair]
#pragma unroll
    for (int mt = 0; mt < 2; ++mt) {
      const unsigned short* wr0 = Wm + (16 * mt + c) * 64 + 8 * q;
      bf16x8 a0 = *reinterpret_cast<const bf16x8*>(wr0);
      bf16x8 a1 = *reinterpret_cast<const bf16x8*>(wr0 + 32);
      float4 bb = *reinterpret_cast<const float4*>(Bp + 32 * w + 16 * mt + 4 * q);
#pragma unroll
      for (int nt = 0; nt < 3; ++nt) {
        f32x4 acc = mfma16(a1, xf[nt][1], mfma16(a0, xf[nt][0], z4));
        qk[nt][mt][0] = pk2(acc[0] + bb.x, acc[1] + bb.y);
        qk[nt][mt][1] = pk2(acc[2] + bb.z, acc[3] + bb.w);
      }
    }
#pragma unroll
    for (int gt = 0; gt < 3; ++gt) {
      V8 f;
#pragma unroll
      for (int a = 0; a < 4; ++a) {
        int src = (a < 2) ? srcA0 : srcA1;
        unsigned v0 = (unsigned)__shfl((int)qk[gt][0][a & 1], src, 64);
        unsigned v1 = (unsigned)__shfl((int)qk[gt][1][a & 1], src, 64);
        f.u[a] = (q < 2) ? v0 : v1;                          // mt = q>>1
      }
      if (pr) kf[gt] = f.v; else qf[gt] = f.v;
    }
  }

  // ---------- Phase C: S^T = K Q^T (all-register), softmax over g ----------
  f32x4 s[3][3];
#pragma unroll
  for (int gt = 0; gt < 3; ++gt)
#pragma unroll
    for (int ft = 0; ft < 3; ++ft)
      s[gt][ft] = mfma16(kf[gt], qf[ft], z4);                // row g=16gt+4q+r, col f

  // softmax fused with P C-layout -> A-operand quad-shuffle (pp transient)
  bf16x8 pf[3][2];
  const float cexp = 0.125f * 1.44269504f;                   // 1/sqrt(64) * log2(e)
#pragma unroll
  for (int ft = 0; ft < 3; ++ft) {
    float m = -1e30f;
#pragma unroll
    for (int gt = 0; gt < 2; ++gt)
#pragma unroll
      for (int r = 0; r < 4; ++r) m = fmaxf(m, s[gt][ft][r]);
    if (q < 2) {
#pragma unroll
      for (int r = 0; r < 4; ++r) m = fmaxf(m, s[2][ft][r]);
    }
    m = fmaxf(m, __shfl_xor(m, 16, 64));
    m = fmaxf(m, __shfl_xor(m, 32, 64));
    float p[3][4]; float sum = 0.f;
#pragma unroll
    for (int gt = 0; gt < 3; ++gt)
#pragma unroll
      for (int r = 0; r < 4; ++r) {
        float pe = EXP2F((s[gt][ft][r] - m) * cexp);
        if (gt == 2 && q >= 2) pe = 0.f;                     // mask g=40..47
        p[gt][r] = pe; sum += pe;
      }
    sum += __shfl_xor(sum, 16, 64);
    sum += __shfl_xor(sum, 32, 64);
    float inv = RCPF(sum);
    unsigned pp[3][2];
#pragma unroll
    for (int gt = 0; gt < 3; ++gt) {
      pp[gt][0] = pk2(p[gt][0] * inv, p[gt][1] * inv);
      pp[gt][1] = pk2(p[gt][2] * inv, p[gt][3] * inv);
    }
    V8 f0, f1;
#pragma unroll
    for (int a = 0; a < 4; ++a) {
      int src = (a < 2) ? srcA0 : srcA1;
      unsigned v0 = (unsigned)__shfl((int)pp[0][a & 1], src, 64);
      unsigned v1 = (unsigned)__shfl((int)pp[1][a & 1], src, 64);
      unsigned v2 = (unsigned)__shfl((int)pp[2][a & 1], src, 64);
      f0.u[a] = (q < 2) ? v0 : v1;                           // ks=0: gt'=q>>1
      f1.u[a] = (q < 2) ? v2 : 0u;                           // ks=1: gt'=2 or zero
    }
    pf[ft][0] = f0.v; pf[ft][1] = f1.v;
  }

  // ---------- Phase D: O = P V ----------
  f32x4 o[3][2];
  {
    bf16x8 vb[2][2];
#pragma unroll
    for (int nt = 0; nt < 2; ++nt)
#pragma unroll
      for (int ks = 0; ks < 2; ++ks)
        vb[nt][ks] = lds_ld16(Vtb + (c + 16 * nt) * VTS + 32 * ks + 8 * q);
#pragma unroll
    for (int mt = 0; mt < 3; ++mt)
#pragma unroll
      for (int nt = 0; nt < 2; ++nt)
        o[mt][nt] = mfma16(pf[mt][1], vb[nt][1], mfma16(pf[mt][0], vb[nt][0], z4));
  }

  // ---------- Phase E: relu(O + R) -> block-shared LDS stage -> linear copy ----
  __syncthreads();   // barrier #2: xb + all Vt now dead; whole LDS reusable
  float* os = reinterpret_cast<float*>(sm);                  // [40][132] f32
  float brv0 = br[32 * w + c], brv1 = br[32 * w + c + 16];
#pragma unroll
  for (int mt = 0; mt < 3; ++mt) {
    if (mt < 2 || q < 2) {
#pragma unroll
      for (int nt = 0; nt < 2; ++nt) {
        float bb = nt ? brv1 : brv0;
#pragma unroll
        for (int r = 0; r < 4; ++r) {
          int f = 16 * mt + 4 * q + r;
          unsigned pr_ = rp[mt][nt][r >> 1];
          float rv = bf2f((unsigned short)((r & 1) ? (pr_ >> 16) : (pr_ & 0xFFFFu)));
          os[f * OSS + 32 * w + c + 16 * nt] = fmaxf(o[mt][nt][r] + rv + bb, 0.f);
        }
      }
    }
  }
  __syncthreads();   // barrier #3: stage complete (rows span all waves)
  // cooperative linear copy: per instr each wave stores 1KB contiguous ->
  // every 256B L2 sector written atomically by one instruction (no RMW).
  float* ob = out + (size_t)b * (F_DIM * O_DIM);
#pragma unroll
  for (int it = 0; it < 5; ++it) {
    int v = (256 * it + t) * 4;                              // flat float idx
    int f = v >> 7, d = v & 127;
    float4 val = *reinterpret_cast<const float4*>(os + f * OSS + d);
    *reinterpret_cast<float4*>(ob + v) = val;
  }
}

extern "C" void kernel_launch(void* const* d_in, const int* in_sizes, int n_in,
                              void* d_out, int out_size, void* d_ws, size_t ws_size,
                              hipStream_t stream) {
  const float* x  = (const float*)d_in[0];
  const float* Wq = (const float*)d_in[1];
  const float* bq = (const float*)d_in[2];
  const float* Wk = (const float*)d_in[3];
  const float* bk = (const float*)d_in[4];
  const float* Wv = (const float*)d_in[5];
  const float* bv = (const float*)d_in[6];
  const float* Wr = (const float*)d_in[7];
  const float* br = (const float*)d_in[8];
  unsigned short* wbf = (unsigned short*)d_ws;               // 32768 bf16 = 64 KB
  float* out = (float*)d_out;
  convert_weights<<<128, 256, 0, stream>>>(Wq, Wk, Wv, Wr, wbf);
  interact_kernel<<<16384, 256, 0, stream>>>(x, wbf, bq, bk, bv, br, out);
}

// Round 5
// 547.329 us; speedup vs baseline: 1.1576x; 1.1083x over previous
//
#include <hip/hip_runtime.h>
#include <hip/hip_bf16.h>

// InteractingLayer: B=16384, F=40, E=64, H=4, D=32, OUT=128
// One block (256 thr, 4 waves) per batch element. Wave w owns head w
// END-TO-END: computes Q/K/V/R column-slices [32w,32w+32) itself, then does
// head-w attention. Q/K NEVER touch LDS (C-layout -> A/B-operand via quad
// shuffles). LDS = x-staging + per-head Vt: 24960 B.
// R5 epilogue: block-shared [40][132] fp32 stage after barrier #2, then
// cooperative linear copy (1KB contiguous per wave-instr, sector-atomic).
// R6: __launch_bounds__(256,6) -> (256,4). Evidence for spilling under the
// 6-wave bound: VGPR_Count fell 68->40 in R2 while live register state GREW,
// and WRITE_SIZE gained +240MiB (1.75x output) with +90MiB FETCH - scratch
// spill traffic, which also explains why 2x occupancy bought zero time.
// Cap 4 waves/SIMD (VGPR<=128): spill-free codegen, 4 blocks/CU via VGPR,
// LDS no longer binding.

#define F_DIM 40
#define O_DIM 128

typedef __bf16 bf16x8 __attribute__((ext_vector_type(8)));
typedef __bf16 bf16x2 __attribute__((ext_vector_type(2)));
typedef float  f32x4  __attribute__((ext_vector_type(4)));

// ---- LDS map (ushort units) ----
// xb [48][68] @ 0 (3264)  shared x staging (bf16), rows 40..47 zeroed
//   stride 68 ushort = 136 B = 34 banks (≡2 mod 32)
// per head h @ 3264 + h*2304 (wave-private):
//   Vt [32][72]  cols 48..63 zeroed; 64..71 pad (never read by PV)
// After barrier #2: whole block reused as ONE block-shared fp32 out-stage
//   os = [40][132] f32 (21120 B)
#define XBS 68
#define VTS 72
#define OSS 132
#define HB0 3264
#define HSZ 2304
#define TOT 12480   // ushorts = 24960 B

static __device__ __forceinline__ unsigned pk2(float a, float b) {
  // native f32->bf16 (RNE) pair -> compiler emits one v_cvt_pk_bf16_f32
  bf16x2 t;
  t[0] = (__bf16)a;
  t[1] = (__bf16)b;
  return __builtin_bit_cast(unsigned, t);
}
static __device__ __forceinline__ float bf2f(unsigned short h) {
  unsigned u = ((unsigned)h) << 16;
  return __builtin_bit_cast(float, u);
}
union V8 { uint2 u2[2]; uint4 u4; unsigned u[4]; bf16x8 v; };
static __device__ __forceinline__ bf16x8 lds_ld8(const unsigned short* p) {   // 8B-aligned
  V8 t; t.u2[0] = *(const uint2*)p; t.u2[1] = *(const uint2*)(p + 4); return t.v;
}
static __device__ __forceinline__ bf16x8 lds_ld16(const unsigned short* p) {  // 16B-aligned
  V8 t; t.u4 = *(const uint4*)p; return t.v;
}
static __device__ __forceinline__ f32x4 mfma16(bf16x8 a, bf16x8 b, f32x4 c) {
  return __builtin_amdgcn_mfma_f32_16x16x32_bf16(a, b, c, 0, 0, 0);
}

#if __has_builtin(__builtin_amdgcn_exp2f)
#define EXP2F __builtin_amdgcn_exp2f
#else
#define EXP2F exp2f
#endif
#if __has_builtin(__builtin_amdgcn_rcpf)
#define RCPF __builtin_amdgcn_rcpf
#else
#define RCPF(x) (1.0f / (x))
#endif

__global__ void convert_weights(const float* __restrict__ Wq, const float* __restrict__ Wk,
                                const float* __restrict__ Wv, const float* __restrict__ Wr,
                                unsigned short* __restrict__ ws) {
  int i = blockIdx.x * 256 + threadIdx.x;   // 0..32767
  const float* src = (i < 8192) ? Wq : (i < 16384) ? Wk : (i < 24576) ? Wv : Wr;
  ws[i] = __builtin_bit_cast(unsigned short, (__bf16)src[i & 8191]);
}

__global__ __launch_bounds__(256, 4) void interact_kernel(
    const float* __restrict__ x, const unsigned short* __restrict__ wbf,
    const float* __restrict__ bq, const float* __restrict__ bk,
    const float* __restrict__ bv, const float* __restrict__ br,
    float* __restrict__ out) {
  __shared__ __align__(16) unsigned short sm[TOT];
  const int t = threadIdx.x;
  const int w = t >> 6;        // wave = head
  const int l = t & 63;
  const int c = l & 15;        // MFMA lane-column
  const int q = l >> 4;        // quad
  const int b = blockIdx.x;
  f32x4 z4 = {0.f, 0.f, 0.f, 0.f};

  // quad-shuffle source lanes for all C-layout -> A/B-operand transforms:
  // target (c,q) elem pair a pulls from lane 16*(2(q&1)+(a>>1)) + c
  const int srcA0 = 16 * (2 * (q & 1) + 0) + c;   // a = 0,1
  const int srcA1 = 16 * (2 * (q & 1) + 1) + c;   // a = 2,3

  // ---------- Phase A: stage x -> LDS bf16 (shared); zero pad rows ----------
  const float* xp = x + (size_t)b * (F_DIM * 64);
  for (int i = t; i < 640; i += 256) {                       // 640 float4 = 40x64
    float4 v4 = reinterpret_cast<const float4*>(xp)[i];
    int f = i >> 4, e4 = (i & 15) << 2;
    uint2 pk; pk.x = pk2(v4.x, v4.y); pk.y = pk2(v4.z, v4.w);
    *reinterpret_cast<uint2*>(sm + f * XBS + e4) = pk;
  }
  {
    uint2 z; z.x = 0; z.y = 0;
    for (int i = t; i < 136; i += 256)                       // rows 40..47 = 0 (8*68/4)
      reinterpret_cast<uint2*>(sm + 40 * XBS)[i] = z;
  }
  __syncthreads();                                           // barrier #1

  unsigned short* Vtb = sm + HB0 + w * HSZ;

  // x fragments: rows f=c+16t, k=e in quads. Serves as A- and B-operand.
  bf16x8 xf[3][2];
#pragma unroll
  for (int nt = 0; nt < 3; ++nt)
#pragma unroll
    for (int ks = 0; ks < 2; ++ks)
      xf[nt][ks] = lds_ld8(sm + (c + 16 * nt) * XBS + 32 * ks + 8 * q);

  // ---------- Phase B ----------
  // V: D[f][d] (A=x rows f, B=W rows d); store transposed Vt[d][f] in LDS
#pragma unroll
  for (int nt = 0; nt < 2; ++nt) {
    const unsigned short* wr0 = wbf + 2 * 8192 + (32 * w + 16 * nt + c) * 64 + 8 * q;
    bf16x8 b0 = *reinterpret_cast<const bf16x8*>(wr0);
    bf16x8 b1 = *reinterpret_cast<const bf16x8*>(wr0 + 32);
    float bb = bv[32 * w + c + 16 * nt];
#pragma unroll
    for (int mt = 0; mt < 3; ++mt) {
      f32x4 acc = mfma16(xf[mt][1], b1, mfma16(xf[mt][0], b0, z4));
      uint2 pk;
      pk.x = pk2(acc[0] + bb, acc[1] + bb);
      pk.y = pk2(acc[2] + bb, acc[3] + bb);
      *reinterpret_cast<uint2*>(Vtb + (c + 16 * nt) * VTS + 16 * mt + 4 * q) = pk;
    }
  }
  {
    uint2 zz; zz.x = 0; zz.y = 0;                            // Vt[:,48..63] = 0
#pragma unroll
    for (int k2 = 0; k2 < 2; ++k2) {
      int idx = l + 64 * k2, row = idx >> 2, g4 = idx & 3;
      *reinterpret_cast<uint2*>(Vtb + row * VTS + 48 + 4 * g4) = zz;
    }
  }
  // R: D[f][d] — same layout as O; keep packed bf16 in registers (12 VGPR)
  unsigned rp[3][2][2];
#pragma unroll
  for (int nt = 0; nt < 2; ++nt) {
    const unsigned short* wr0 = wbf + 3 * 8192 + (32 * w + 16 * nt + c) * 64 + 8 * q;
    bf16x8 b0 = *reinterpret_cast<const bf16x8*>(wr0);
    bf16x8 b1 = *reinterpret_cast<const bf16x8*>(wr0 + 32);
#pragma unroll
    for (int mt = 0; mt < 3; ++mt) {
      f32x4 acc = mfma16(xf[mt][1], b1, mfma16(xf[mt][0], b0, z4));
      rp[mt][nt][0] = pk2(acc[0], acc[1]);
      rp[mt][nt][1] = pk2(acc[2], acc[3]);
    }
  }
  // Q,K: D[d][f] (A=W rows d, B=x rows f). Never stored: pack + quad-shuffle
  // straight into A/B-operand fragments (rows f=c+16gt, k=d=8q+j).
  //   target pair a: d=8q+2a -> src mt = q>>1, src quad 2(q&1)+(a>>1), pair a&1
  // Rows f in [40,48) come from zeroed x rows -> bias-only, finite; masked in
  // softmax (g-mask) / never stored (f-mask).
  bf16x8 qf[3], kf[3];
#pragma unroll
  for (int pr = 0; pr < 2; ++pr) {
    const unsigned short* Wm = wbf + pr * 8192 + 32 * w * 64;
    const float* Bp = pr ? bk : bq;
    unsigned qk[3][2][2];                                    // [nt=f-tile][mt][pair]
#pragma unroll
    for (int mt = 0; mt < 2; ++mt) {
      const unsigned short* wr0 = Wm + (16 * mt + c) * 64 + 8 * q;
      bf16x8 a0 = *reinterpret_cast<const bf16x8*>(wr0);
      bf16x8 a1 = *reinterpret_cast<const bf16x8*>(wr0 + 32);
      float4 bb = *reinterpret_cast<const float4*>(Bp + 32 * w + 16 * mt + 4 * q);
#pragma unroll
      for (int nt = 0; nt < 3; ++nt) {
        f32x4 acc = mfma16(a1, xf[nt][1], mfma16(a0, xf[nt][0], z4));
        qk[nt][mt][0] = pk2(acc[0] + bb.x, acc[1] + bb.y);
        qk[nt][mt][1] = pk2(acc[2] + bb.z, acc[3] + bb.w);
      }
    }
#pragma unroll
    for (int gt = 0; gt < 3; ++gt) {
      V8 f;
#pragma unroll
      for (int a = 0; a < 4; ++a) {
        int src = (a < 2) ? srcA0 : srcA1;
        unsigned v0 = (unsigned)__shfl((int)qk[gt][0][a & 1], src, 64);
        unsigned v1 = (unsigned)__shfl((int)qk[gt][1][a & 1], src, 64);
        f.u[a] = (q < 2) ? v0 : v1;                          // mt = q>>1
      }
      if (pr) kf[gt] = f.v; else qf[gt] = f.v;
    }
  }

  // ---------- Phase C: S^T = K Q^T (all-register), softmax over g ----------
  f32x4 s[3][3];
#pragma unroll
  for (int gt = 0; gt < 3; ++gt)
#pragma unroll
    for (int ft = 0; ft < 3; ++ft)
      s[gt][ft] = mfma16(kf[gt], qf[ft], z4);                // row g=16gt+4q+r, col f

  // softmax fused with P C-layout -> A-operand quad-shuffle (pp transient)
  bf16x8 pf[3][2];
  const float cexp = 0.125f * 1.44269504f;                   // 1/sqrt(64) * log2(e)
#pragma unroll
  for (int ft = 0; ft < 3; ++ft) {
    float m = -1e30f;
#pragma unroll
    for (int gt = 0; gt < 2; ++gt)
#pragma unroll
      for (int r = 0; r < 4; ++r) m = fmaxf(m, s[gt][ft][r]);
    if (q < 2) {
#pragma unroll
      for (int r = 0; r < 4; ++r) m = fmaxf(m, s[2][ft][r]);
    }
    m = fmaxf(m, __shfl_xor(m, 16, 64));
    m = fmaxf(m, __shfl_xor(m, 32, 64));
    float p[3][4]; float sum = 0.f;
#pragma unroll
    for (int gt = 0; gt < 3; ++gt)
#pragma unroll
      for (int r = 0; r < 4; ++r) {
        float pe = EXP2F((s[gt][ft][r] - m) * cexp);
        if (gt == 2 && q >= 2) pe = 0.f;                     // mask g=40..47
        p[gt][r] = pe; sum += pe;
      }
    sum += __shfl_xor(sum, 16, 64);
    sum += __shfl_xor(sum, 32, 64);
    float inv = RCPF(sum);
    unsigned pp[3][2];
#pragma unroll
    for (int gt = 0; gt < 3; ++gt) {
      pp[gt][0] = pk2(p[gt][0] * inv, p[gt][1] * inv);
      pp[gt][1] = pk2(p[gt][2] * inv, p[gt][3] * inv);
    }
    V8 f0, f1;
#pragma unroll
    for (int a = 0; a < 4; ++a) {
      int src = (a < 2) ? srcA0 : srcA1;
      unsigned v0 = (unsigned)__shfl((int)pp[0][a & 1], src, 64);
      unsigned v1 = (unsigned)__shfl((int)pp[1][a & 1], src, 64);
      unsigned v2 = (unsigned)__shfl((int)pp[2][a & 1], src, 64);
      f0.u[a] = (q < 2) ? v0 : v1;                           // ks=0: gt'=q>>1
      f1.u[a] = (q < 2) ? v2 : 0u;                           // ks=1: gt'=2 or zero
    }
    pf[ft][0] = f0.v; pf[ft][1] = f1.v;
  }

  // ---------- Phase D: O = P V ----------
  f32x4 o[3][2];
  {
    bf16x8 vb[2][2];
#pragma unroll
    for (int nt = 0; nt < 2; ++nt)
#pragma unroll
      for (int ks = 0; ks < 2; ++ks)
        vb[nt][ks] = lds_ld16(Vtb + (c + 16 * nt) * VTS + 32 * ks + 8 * q);
#pragma unroll
    for (int mt = 0; mt < 3; ++mt)
#pragma unroll
      for (int nt = 0; nt < 2; ++nt)
        o[mt][nt] = mfma16(pf[mt][1], vb[nt][1], mfma16(pf[mt][0], vb[nt][0], z4));
  }

  // ---------- Phase E: relu(O + R) -> block-shared LDS stage -> linear copy ----
  __syncthreads();   // barrier #2: xb + all Vt now dead; whole LDS reusable
  float* os = reinterpret_cast<float*>(sm);                  // [40][132] f32
  float brv0 = br[32 * w + c], brv1 = br[32 * w + c + 16];
#pragma unroll
  for (int mt = 0; mt < 3; ++mt) {
    if (mt < 2 || q < 2) {
#pragma unroll
      for (int nt = 0; nt < 2; ++nt) {
        float bb = nt ? brv1 : brv0;
#pragma unroll
        for (int r = 0; r < 4; ++r) {
          int f = 16 * mt + 4 * q + r;
          unsigned pr_ = rp[mt][nt][r >> 1];
          float rv = bf2f((unsigned short)((r & 1) ? (pr_ >> 16) : (pr_ & 0xFFFFu)));
          os[f * OSS + 32 * w + c + 16 * nt] = fmaxf(o[mt][nt][r] + rv + bb, 0.f);
        }
      }
    }
  }
  __syncthreads();   // barrier #3: stage complete (rows span all waves)
  // cooperative linear copy: per instr each wave stores 1KB contiguous ->
  // every 256B L2 sector written atomically by one instruction (no RMW).
  float* ob = out + (size_t)b * (F_DIM * O_DIM);
#pragma unroll
  for (int it = 0; it < 5; ++it) {
    int v = (256 * it + t) * 4;                              // flat float idx
    int f = v >> 7, d = v & 127;
    float4 val = *reinterpret_cast<const float4*>(os + f * OSS + d);
    *reinterpret_cast<float4*>(ob + v) = val;
  }
}

extern "C" void kernel_launch(void* const* d_in, const int* in_sizes, int n_in,
                              void* d_out, int out_size, void* d_ws, size_t ws_size,
                              hipStream_t stream) {
  const float* x  = (const float*)d_in[0];
  const float* Wq = (const float*)d_in[1];
  const float* bq = (const float*)d_in[2];
  const float* Wk = (const float*)d_in[3];
  const float* bk = (const float*)d_in[4];
  const float* Wv = (const float*)d_in[5];
  const float* bv = (const float*)d_in[6];
  const float* Wr = (const float*)d_in[7];
  const float* br = (const float*)d_in[8];
  unsigned short* wbf = (unsigned short*)d_ws;               // 32768 bf16 = 64 KB
  float* out = (float*)d_out;
  convert_weights<<<128, 256, 0, stream>>>(Wq, Wk, Wv, Wr, wbf);
  interact_kernel<<<16384, 256, 0, stream>>>(x, wbf, bq, bk, bv, br, out);
}